// Round 14
// baseline (121.071 us; speedup 1.0000x reference)
//
#include <hip/hip_runtime.h>

typedef unsigned short u16;
typedef __attribute__((ext_vector_type(8))) short short8;
typedef __attribute__((ext_vector_type(4))) float f32x4;

#define GLL16(g, l) __builtin_amdgcn_global_load_lds(                         \
    (const __attribute__((address_space(1))) void*)(g),                        \
    (__attribute__((address_space(3))) void*)(l), 16, 0, 0)

__device__ __forceinline__ u16 f2bf(float f) {
  union { float f; unsigned u; } v; v.f = f;
  unsigned u = v.u;
  return (u16)((u + 0x7FFFu + ((u >> 16) & 1u)) >> 16);  // RNE
}

__device__ __forceinline__ float bf2f(u16 u) {
  union { unsigned u; float f; } v; v.u = ((unsigned)u) << 16;
  return v.f;
}

__device__ __forceinline__ ushort4 cvt4(float4 v) {
  ushort4 o; o.x = f2bf(v.x); o.y = f2bf(v.y); o.z = f2bf(v.z); o.w = f2bf(v.w);
  return o;
}

// ---------------------------------------------------------------------------
// Kernel PRE: x->bf16 + fp32 router logits; W_base/A_w/B_w converts. (R11)
// ---------------------------------------------------------------------------
__global__ __launch_bounds__(512) void k_pre(
    const float* __restrict__ x, const float* __restrict__ Wr,
    const float* __restrict__ Wb, const float* __restrict__ Aw,
    const float* __restrict__ Bw,
    u16* __restrict__ xbf, float* __restrict__ logits,
    u16* __restrict__ wbf, u16* __restrict__ aabf, u16* __restrict__ bmt)
{
  __shared__ float wlds[16384];  // 8 x 2048 fp32 = 64 KB
  {
    const float4* src = (const float4*)Wr;
    float4* dst = (float4*)wlds;
    int t = threadIdx.x;
#pragma unroll
    for (int i = 0; i < 8; ++i) dst[t + i * 512] = src[t + i * 512];
  }
  __syncthreads();
  const int wave = threadIdx.x >> 6, lane = threadIdx.x & 63;
  const float4* wv = (const float4*)wlds;
#pragma unroll 1
  for (int s = 0; s < 2; ++s) {
    int tok = blockIdx.x * 16 + wave * 2 + s;
    const float4* xrow = (const float4*)(x + tok * 2048);
    ushort4* orow = (ushort4*)(xbf + tok * 2048);
    float acc[8];
#pragma unroll
    for (int e = 0; e < 8; ++e) acc[e] = 0.f;
#pragma unroll 1
    for (int i = 0; i < 8; ++i) {
      float4 xv = xrow[lane + i * 64];
      orow[lane + i * 64] = cvt4(xv);
#pragma unroll
      for (int e = 0; e < 8; ++e) {
        float4 b = wv[e * 512 + lane + i * 64];
        acc[e] += xv.x * b.x + xv.y * b.y + xv.z * b.z + xv.w * b.w;
      }
    }
#pragma unroll
    for (int e = 0; e < 8; ++e) {
      float v = acc[e];
#pragma unroll
      for (int off = 32; off > 0; off >>= 1) v += __shfl_xor(v, off, 64);
      acc[e] = v;
    }
    if (lane == 0) {
#pragma unroll
      for (int e = 0; e < 8; ++e) logits[tok * 8 + e] = acc[e];
    }
  }
  // ---- weight conversions
  const int tidg = blockIdx.x * 512 + threadIdx.x;
  {
    const float4* src = (const float4*)Wb;   // 1,048,576 float4
    ushort4* dst = (ushort4*)wbf;
#pragma unroll
    for (int i = 0; i < 4; ++i)
      dst[tidg + i * 262144] = cvt4(src[tidg + i * 262144]);
  }
  if (tidg < 32768) {                        // A_w: 32768 float4
    ((ushort4*)aabf)[tidg] = cvt4(((const float4*)Aw)[tidg]);
  }
  if (tidg < 2048) {                         // B_w [8][2048][8] -> bmt [2048][64]
    const int n = tidg;
#pragma unroll
    for (int e = 0; e < 8; ++e) {
      const float4* src = (const float4*)(Bw + e * 16384 + n * 8);
      ushort4* dst = (ushort4*)(bmt + n * 64 + e * 8);
      dst[0] = cvt4(src[0]);
      dst[1] = cvt4(src[1]);
    }
  }
}

// ---------------------------------------------------------------------------
// Kernel C: h partials (bf16), split-K=8. (R11)
// ---------------------------------------------------------------------------
__global__ __launch_bounds__(256) void k_hgemm(
    const u16* __restrict__ xbf, const u16* __restrict__ aabf,
    u16* __restrict__ P)
{
  __shared__ u16 As[256 * 64];
  __shared__ u16 Bs[64 * 64];
  int t = threadIdx.x, wave = t >> 6, lane = t & 63;
  int mBase = blockIdx.x * 256;
  int ks = blockIdx.y;
  int fr = lane & 15, fg = lane >> 4;
  int lrow = lane >> 3, lcol = (lane & 7) * 8;
  f32x4 zero = {0.f, 0.f, 0.f, 0.f};
  f32x4 acc[4][4];
#pragma unroll
  for (int i = 0; i < 4; ++i)
#pragma unroll
    for (int j = 0; j < 4; ++j) acc[i][j] = zero;
#pragma unroll 1
  for (int it = 0; it < 4; ++it) {
    int k0 = ks * 256 + it * 64;
    __syncthreads();
#pragma unroll
    for (int cc = 0; cc < 8; ++cc) {
      int c = wave * 8 + cc;
      GLL16(xbf + (mBase + c * 8 + lrow) * 2048 + k0 + lcol, &As[c * 512]);
    }
#pragma unroll
    for (int cc = 0; cc < 2; ++cc) {
      int c = wave * 2 + cc;
      GLL16(aabf + (c * 8 + lrow) * 2048 + k0 + lcol, &Bs[c * 512]);
    }
    __syncthreads();
#pragma unroll
    for (int kk = 0; kk < 2; ++kk) {
      short8 a[4], bfr[4];
#pragma unroll
      for (int i = 0; i < 4; ++i)
        a[i] = *(const short8*)&As[(wave * 64 + i * 16 + fr) * 64 + kk * 32 + fg * 8];
#pragma unroll
      for (int j = 0; j < 4; ++j)
        bfr[j] = *(const short8*)&Bs[(j * 16 + fr) * 64 + kk * 32 + fg * 8];
#pragma unroll
      for (int i = 0; i < 4; ++i)
#pragma unroll
        for (int j = 0; j < 4; ++j)
          acc[i][j] = __builtin_amdgcn_mfma_f32_16x16x32_bf16(a[i], bfr[j], acc[i][j], 0, 0, 0);
    }
  }
#pragma unroll
  for (int i = 0; i < 4; ++i)
#pragma unroll
    for (int j = 0; j < 4; ++j)
#pragma unroll
      for (int r = 0; r < 4; ++r) {
        int m = mBase + wave * 64 + i * 16 + fg * 4 + r;
        int n = j * 16 + fr;
        P[(ks * 8192 + m) * 64 + n] = f2bf(acc[i][j][r]);
      }
}

// ---------------------------------------------------------------------------
// Kernel D: top-2 softmax gates; reduce bf16 split-K partials -> G. (R11)
// ---------------------------------------------------------------------------
__global__ __launch_bounds__(256) void k_topk(
    const float* __restrict__ logits, const u16* __restrict__ P,
    u16* __restrict__ G)
{
  int t = threadIdx.x, wave = t >> 6, lane = t & 63;
  int tok = blockIdx.x * 4 + wave;
  const float* lg = logits + tok * 8;
  float la[8];
#pragma unroll
  for (int e = 0; e < 8; ++e) la[e] = lg[e];
  float v0 = la[0]; int i0 = 0;
#pragma unroll
  for (int e = 1; e < 8; ++e) { if (la[e] > v0) { v0 = la[e]; i0 = e; } }
  float v1 = -3.4e38f; int i1 = 0;
#pragma unroll
  for (int e = 0; e < 8; ++e) { if (e != i0 && la[e] > v1) { v1 = la[e]; i1 = e; } }
  float ex = expf(v1 - v0);
  float inv = 1.f / (1.f + ex);
  float gate0 = inv, gate1 = ex * inv;
  int e = lane >> 3;
  float h = 0.f;
#pragma unroll
  for (int ks = 0; ks < 8; ++ks) h += bf2f(P[(ks * 8192 + tok) * 64 + lane]);
  float g = (e == i0) ? gate0 : ((e == i1) ? gate1 : 0.f);
  G[tok * 64 + lane] = f2bf(2.0f * g * h);  // SCALE = alpha/r = 2
}

// ---------------------------------------------------------------------------
// Kernel E: main GEMM, 128x128 tile, BK=64, 3 BLOCKS/CU (deeper slip).
// K = 2048 (tiles 0..31) + virtual LoRA K-tile 32 (A=G, B=BmT, ld=64).
// 256 thr (4 waves 2Mx2N, per-wave 64x64, acc 64 VGPR). LDS 48KB:
// A single-buf 16KB + B double-buf 2x16KB -> 3 blocks/CU (144KB).
// Per tile (2 barriers, 1 vmcnt, counted lgkm; reads 16 at p0):
//   p0: VMC(0)[t's stages landed] BAR | rd U(B01,4) A(8) V(B23,4) |
//       LGKM(4)[U+A retired, V in flight] | MFMA nj01 (16) | BAR
//   p1: stage B(t+1)->Bnxt + A(t+1)->Abuf (8 gll) | LGKM(0) | MFMA nj23 (16)
// Safety: A(t) reads retired at p0's LGKM(4) before p0-end BAR -> A stage at
// p1 legal (single A-buf). Bnxt last read tile t-1 p0/p1, retired by t-1
// LGKM(0) + t p0 BAR -> B stage at p1 legal. Stages land by next p0's VMC(0).
// Per-acc FP order identical to R13 -> bitwise-identical output.
// ---------------------------------------------------------------------------
__global__ __launch_bounds__(256, 3) void k_main(
    const u16* __restrict__ xbf, const u16* __restrict__ wbf,
    const u16* __restrict__ G, const u16* __restrict__ BmT,
    const float* __restrict__ bias, float* __restrict__ out)
{
  __shared__ u16 lds[24576];  // A:[0,8192) B0:[8192,16384) B1:[16384,24576)
  const int tid = threadIdx.x;
  const int w = tid >> 6, lane = tid & 63;
  const int fr = lane & 15, fg = lane >> 4;
  const int wr = w >> 1, wc = w & 1;

  // XCD map (1024 blocks, %8==0 bijective): xcd-major m-groups, n-minor
  const int b0 = blockIdx.x;
  const int xcd = b0 & 7, ii = b0 >> 3;           // ii 0..127
  const int mBase = (xcd * 8 + (ii >> 4)) * 128;  // 64 m-tiles
  const int nBase = (ii & 15) * 128;              // 16 n-tiles

  // staging addressing (linear LDS dest; swizzled global source col)
  const int rl = lane >> 3;                 // 0..7
  const int ce = ((lane & 7) ^ rl) << 3;    // source col elems (XOR swizzle)
  // ds_read addressing (same XOR involution)
  const int swz = (fr & 7) << 3;
  const int colk0 = (fg * 8) ^ swz;
  const int colk1 = (32 + fg * 8) ^ swz;
  const int aOff = (wr * 64 + fr) * 64;
  const int bOff = (wc * 64 + fr) * 64;

  // running source pointers (+=64 per tile staged)
  const u16* pA = xbf + (mBase + w * 32 + rl) * 2048 + ce;
  const u16* pB = wbf + (nBase + w * 32 + rl) * 2048 + ce;

  f32x4 acc[4][4];  // [mi][nj]
  const f32x4 zero = {0.f, 0.f, 0.f, 0.f};
#pragma unroll
  for (int mi = 0; mi < 4; ++mi)
#pragma unroll
    for (int nj = 0; nj < 4; ++nj) acc[mi][nj] = zero;

  short8 a[4][2];            // A(t) fragments (held p0->p1)
  short8 U[2][2], V[2][2];   // B nj-pair fragments

#define LGKM(N) asm volatile("s_waitcnt lgkmcnt(" #N ")" ::: "memory")
#define VMC(N)  asm volatile("s_waitcnt vmcnt(" #N ")" ::: "memory")
#define BAR()   __builtin_amdgcn_s_barrier()

  // stage A(next): 4 GLL16, rows w*32 + q*8 + rl, dst linear A-buf
#define SA() { GLL16(pA,         lds + w * 2048);                             \
               GLL16(pA + 16384, lds + w * 2048 + 512);                       \
               GLL16(pA + 32768, lds + w * 2048 + 1024);                      \
               GLL16(pA + 49152, lds + w * 2048 + 1536);                      \
               pA += 64; }
  // stage B(next) into buffer at u16-offset BOFF
#define SB(BOFF) { GLL16(pB,         lds + (BOFF) + w * 2048);                \
                   GLL16(pB + 16384, lds + (BOFF) + w * 2048 + 512);          \
                   GLL16(pB + 32768, lds + (BOFF) + w * 2048 + 1024);         \
                   GLL16(pB + 49152, lds + (BOFF) + w * 2048 + 1536);         \
                   pB += 64; }

#define RDA()                                                                 \
  _Pragma("unroll")                                                           \
  for (int mi = 0; mi < 4; ++mi) {                                            \
    a[mi][0] = *(const short8*)(lds + aOff + mi * 1024 + colk0);              \
    a[mi][1] = *(const short8*)(lds + aOff + mi * 1024 + colk1);              \
  }

#define RDB2(DST, BOFF, NJ0)                                                  \
  DST[0][0] = *(const short8*)(lds + (BOFF) + bOff + (NJ0) * 1024 + colk0);   \
  DST[0][1] = *(const short8*)(lds + (BOFF) + bOff + (NJ0) * 1024 + colk1);   \
  DST[1][0] = *(const short8*)(lds + (BOFF) + bOff + ((NJ0)+1) * 1024 + colk0);\
  DST[1][1] = *(const short8*)(lds + (BOFF) + bOff + ((NJ0)+1) * 1024 + colk1);

#define MFMAP(BV, NJ0)                                                        \
  __builtin_amdgcn_s_setprio(1);                                              \
  _Pragma("unroll")                                                           \
  for (int kk = 0; kk < 2; ++kk)                                              \
    _Pragma("unroll")                                                         \
    for (int mi = 0; mi < 4; ++mi)                                            \
      _Pragma("unroll")                                                       \
      for (int j = 0; j < 2; ++j)                                             \
        acc[mi][(NJ0) + j] = __builtin_amdgcn_mfma_f32_16x16x32_bf16(         \
            a[mi][kk], BV[j][kk], acc[mi][(NJ0) + j], 0, 0, 0);               \
  __builtin_amdgcn_s_setprio(0);

#define TILE(BCUR, SBS, SAS)                                                  \
  {                                                                           \
    /* p0 */                                                                  \
    VMC(0);                                                                   \
    BAR();                                                                    \
    RDB2(U, BCUR, 0)                                                          \
    RDA()                                                                     \
    RDB2(V, BCUR, 2)                                                          \
    LGKM(4);                                                                  \
    MFMAP(U, 0)                                                               \
    BAR();                                                                    \
    /* p1 */                                                                  \
    SAS                                                                       \
    SBS                                                                       \
    LGKM(0);                                                                  \
    MFMAP(V, 2)                                                               \
  }

  // ---- prologue: stage A(0) + B(0)->B0 (8 loads); loop p0 drains them
  SA()
  SB(8192)

  // tiles 0..29 (pairs): t even BCUR=B0 stage->B1; t odd BCUR=B1 stage->B0
#pragma unroll 1
  for (int tt = 0; tt < 15; ++tt) {
    TILE(8192, SB(16384), SA())
    TILE(16384, SB(8192), SA())
  }
  // ---- tile 30 (even): regular stages (A31, B31 -> B1)
  TILE(8192, SB(16384), SA())
  // ---- tile 31 (odd): stage A(32)<-G -> A-buf, B(32)<-BmT -> B0
  {
    const u16* pG = G + (mBase + w * 32 + rl) * 64 + ce;
    const u16* pT = BmT + (nBase + w * 32 + rl) * 64 + ce;
    TILE(16384,
         { GLL16(pT,        lds + 8192 + w * 2048);
           GLL16(pT + 512,  lds + 8192 + w * 2048 + 512);
           GLL16(pT + 1024, lds + 8192 + w * 2048 + 1024);
           GLL16(pT + 1536, lds + 8192 + w * 2048 + 1536); },
         { GLL16(pG,        lds + w * 2048);
           GLL16(pG + 512,  lds + w * 2048 + 512);
           GLL16(pG + 1024, lds + w * 2048 + 1024);
           GLL16(pG + 1536, lds + w * 2048 + 1536); })
  }
  // ---- tile 32 (LoRA, even, BCUR=B0): no stages
  TILE(8192, {}, {})

  // ---- epilogue: bias add + store
#pragma unroll
  for (int nj = 0; nj < 4; ++nj) {
    const int n = nBase + wc * 64 + nj * 16 + fr;
    const float bv = bias[n];
#pragma unroll
    for (int mi = 0; mi < 4; ++mi) {
      const int m = mBase + wr * 64 + mi * 16 + fg * 4;
#pragma unroll
      for (int r = 0; r < 4; ++r)
        out[(m + r) * 2048 + n] = acc[mi][nj][r] + bv;
    }
  }
#undef TILE
#undef MFMAP
#undef RDB2
#undef RDA
#undef SB
#undef SA
#undef BAR
#undef VMC
#undef LGKM
}

// ---------------------------------------------------------------------------
extern "C" void kernel_launch(void* const* d_in, const int* in_sizes, int n_in,
                              void* d_out, int out_size, void* d_ws, size_t ws_size,
                              hipStream_t stream) {
  const float* x  = (const float*)d_in[0];   // [4,2048,2048]
  const float* Wb = (const float*)d_in[1];   // [2048,2048]
  const float* bb = (const float*)d_in[2];   // [2048]
  const float* Wr = (const float*)d_in[3];   // [8,2048]
  const float* Aw = (const float*)d_in[4];   // [8,8,2048] == [64][2048]
  const float* Bw = (const float*)d_in[5];   // [8,2048,8]

  char* ws = (char*)d_ws;
  u16*   xbf  = (u16*)  (ws + 0);            // 33,554,432 B
  u16*   wbf  = (u16*)  (ws + 33554432);     //  8,388,608 B
  u16*   aabf = (u16*)  (ws + 41943040);     //    262,144 B
  u16*   bmt  = (u16*)  (ws + 42205184);     //    262,144 B
  float* lgt  = (float*)(ws + 42467328);     //    262,144 B
  u16*   G    = (u16*)  (ws + 42729472);     //  1,048,576 B
  // h-partials [8][8192][64] bf16 (8.4 MB) live in d_out; fully consumed by
  // k_topk before k_main overwrites all of d_out. Same-stream ordering.
  u16*   P   = (u16*)d_out;
  float* out = (float*)d_out;

  hipLaunchKernelGGL(k_pre,   dim3(512),   dim3(512), 0, stream,
                     x, Wr, Wb, Aw, Bw, xbf, lgt, wbf, aabf, bmt);
  hipLaunchKernelGGL(k_hgemm, dim3(32, 8), dim3(256), 0, stream, xbf, aabf, P);
  hipLaunchKernelGGL(k_topk,  dim3(2048),  dim3(256), 0, stream, lgt, P, G);
  hipLaunchKernelGGL(k_main,  dim3(1024),  dim3(256), 0, stream,
                     xbf, wbf, G, bmt, bb, out);
}

// Round 15
// 107.584 us; speedup vs baseline: 1.1254x; 1.1254x over previous
//
#include <hip/hip_runtime.h>

typedef unsigned short u16;
typedef __attribute__((ext_vector_type(8))) short short8;
typedef __attribute__((ext_vector_type(4))) float f32x4;

#define GLL16(g, l) __builtin_amdgcn_global_load_lds(                         \
    (const __attribute__((address_space(1))) void*)(g),                        \
    (__attribute__((address_space(3))) void*)(l), 16, 0, 0)

__device__ __forceinline__ u16 f2bf(float f) {
  union { float f; unsigned u; } v; v.f = f;
  unsigned u = v.u;
  return (u16)((u + 0x7FFFu + ((u >> 16) & 1u)) >> 16);  // RNE
}

__device__ __forceinline__ float bf2f(u16 u) {
  union { unsigned u; float f; } v; v.u = ((unsigned)u) << 16;
  return v.f;
}

__device__ __forceinline__ ushort4 cvt4(float4 v) {
  ushort4 o; o.x = f2bf(v.x); o.y = f2bf(v.y); o.z = f2bf(v.z); o.w = f2bf(v.w);
  return o;
}

// ---------------------------------------------------------------------------
// Kernel PRE: x->bf16 + fp32 router logits; W_base/A_w/B_w converts. (R11)
// ---------------------------------------------------------------------------
__global__ __launch_bounds__(512) void k_pre(
    const float* __restrict__ x, const float* __restrict__ Wr,
    const float* __restrict__ Wb, const float* __restrict__ Aw,
    const float* __restrict__ Bw,
    u16* __restrict__ xbf, float* __restrict__ logits,
    u16* __restrict__ wbf, u16* __restrict__ aabf, u16* __restrict__ bmt)
{
  __shared__ float wlds[16384];  // 8 x 2048 fp32 = 64 KB
  {
    const float4* src = (const float4*)Wr;
    float4* dst = (float4*)wlds;
    int t = threadIdx.x;
#pragma unroll
    for (int i = 0; i < 8; ++i) dst[t + i * 512] = src[t + i * 512];
  }
  __syncthreads();
  const int wave = threadIdx.x >> 6, lane = threadIdx.x & 63;
  const float4* wv = (const float4*)wlds;
#pragma unroll 1
  for (int s = 0; s < 2; ++s) {
    int tok = blockIdx.x * 16 + wave * 2 + s;
    const float4* xrow = (const float4*)(x + tok * 2048);
    ushort4* orow = (ushort4*)(xbf + tok * 2048);
    float acc[8];
#pragma unroll
    for (int e = 0; e < 8; ++e) acc[e] = 0.f;
#pragma unroll 1
    for (int i = 0; i < 8; ++i) {
      float4 xv = xrow[lane + i * 64];
      orow[lane + i * 64] = cvt4(xv);
#pragma unroll
      for (int e = 0; e < 8; ++e) {
        float4 b = wv[e * 512 + lane + i * 64];
        acc[e] += xv.x * b.x + xv.y * b.y + xv.z * b.z + xv.w * b.w;
      }
    }
#pragma unroll
    for (int e = 0; e < 8; ++e) {
      float v = acc[e];
#pragma unroll
      for (int off = 32; off > 0; off >>= 1) v += __shfl_xor(v, off, 64);
      acc[e] = v;
    }
    if (lane == 0) {
#pragma unroll
      for (int e = 0; e < 8; ++e) logits[tok * 8 + e] = acc[e];
    }
  }
  // ---- weight conversions
  const int tidg = blockIdx.x * 512 + threadIdx.x;
  {
    const float4* src = (const float4*)Wb;   // 1,048,576 float4
    ushort4* dst = (ushort4*)wbf;
#pragma unroll
    for (int i = 0; i < 4; ++i)
      dst[tidg + i * 262144] = cvt4(src[tidg + i * 262144]);
  }
  if (tidg < 32768) {                        // A_w: 32768 float4
    ((ushort4*)aabf)[tidg] = cvt4(((const float4*)Aw)[tidg]);
  }
  if (tidg < 2048) {                         // B_w [8][2048][8] -> bmt [2048][64]
    const int n = tidg;
#pragma unroll
    for (int e = 0; e < 8; ++e) {
      const float4* src = (const float4*)(Bw + e * 16384 + n * 8);
      ushort4* dst = (ushort4*)(bmt + n * 64 + e * 8);
      dst[0] = cvt4(src[0]);
      dst[1] = cvt4(src[1]);
    }
  }
}

// ---------------------------------------------------------------------------
// Kernel C: h partials (bf16), split-K=8. (R11)
// ---------------------------------------------------------------------------
__global__ __launch_bounds__(256) void k_hgemm(
    const u16* __restrict__ xbf, const u16* __restrict__ aabf,
    u16* __restrict__ P)
{
  __shared__ u16 As[256 * 64];
  __shared__ u16 Bs[64 * 64];
  int t = threadIdx.x, wave = t >> 6, lane = t & 63;
  int mBase = blockIdx.x * 256;
  int ks = blockIdx.y;
  int fr = lane & 15, fg = lane >> 4;
  int lrow = lane >> 3, lcol = (lane & 7) * 8;
  f32x4 zero = {0.f, 0.f, 0.f, 0.f};
  f32x4 acc[4][4];
#pragma unroll
  for (int i = 0; i < 4; ++i)
#pragma unroll
    for (int j = 0; j < 4; ++j) acc[i][j] = zero;
#pragma unroll 1
  for (int it = 0; it < 4; ++it) {
    int k0 = ks * 256 + it * 64;
    __syncthreads();
#pragma unroll
    for (int cc = 0; cc < 8; ++cc) {
      int c = wave * 8 + cc;
      GLL16(xbf + (mBase + c * 8 + lrow) * 2048 + k0 + lcol, &As[c * 512]);
    }
#pragma unroll
    for (int cc = 0; cc < 2; ++cc) {
      int c = wave * 2 + cc;
      GLL16(aabf + (c * 8 + lrow) * 2048 + k0 + lcol, &Bs[c * 512]);
    }
    __syncthreads();
#pragma unroll
    for (int kk = 0; kk < 2; ++kk) {
      short8 a[4], bfr[4];
#pragma unroll
      for (int i = 0; i < 4; ++i)
        a[i] = *(const short8*)&As[(wave * 64 + i * 16 + fr) * 64 + kk * 32 + fg * 8];
#pragma unroll
      for (int j = 0; j < 4; ++j)
        bfr[j] = *(const short8*)&Bs[(j * 16 + fr) * 64 + kk * 32 + fg * 8];
#pragma unroll
      for (int i = 0; i < 4; ++i)
#pragma unroll
        for (int j = 0; j < 4; ++j)
          acc[i][j] = __builtin_amdgcn_mfma_f32_16x16x32_bf16(a[i], bfr[j], acc[i][j], 0, 0, 0);
    }
  }
#pragma unroll
  for (int i = 0; i < 4; ++i)
#pragma unroll
    for (int j = 0; j < 4; ++j)
#pragma unroll
      for (int r = 0; r < 4; ++r) {
        int m = mBase + wave * 64 + i * 16 + fg * 4 + r;
        int n = j * 16 + fr;
        P[(ks * 8192 + m) * 64 + n] = f2bf(acc[i][j][r]);
      }
}

// ---------------------------------------------------------------------------
// Kernel D: top-2 softmax gates; reduce bf16 split-K partials -> G. (R11)
// ---------------------------------------------------------------------------
__global__ __launch_bounds__(256) void k_topk(
    const float* __restrict__ logits, const u16* __restrict__ P,
    u16* __restrict__ G)
{
  int t = threadIdx.x, wave = t >> 6, lane = t & 63;
  int tok = blockIdx.x * 4 + wave;
  const float* lg = logits + tok * 8;
  float la[8];
#pragma unroll
  for (int e = 0; e < 8; ++e) la[e] = lg[e];
  float v0 = la[0]; int i0 = 0;
#pragma unroll
  for (int e = 1; e < 8; ++e) { if (la[e] > v0) { v0 = la[e]; i0 = e; } }
  float v1 = -3.4e38f; int i1 = 0;
#pragma unroll
  for (int e = 0; e < 8; ++e) { if (e != i0 && la[e] > v1) { v1 = la[e]; i1 = e; } }
  float ex = expf(v1 - v0);
  float inv = 1.f / (1.f + ex);
  float gate0 = inv, gate1 = ex * inv;
  int e = lane >> 3;
  float h = 0.f;
#pragma unroll
  for (int ks = 0; ks < 8; ++ks) h += bf2f(P[(ks * 8192 + tok) * 64 + lane]);
  float g = (e == i0) ? gate0 : ((e == i1) ? gate1 : 0.f);
  G[tok * 64 + lane] = f2bf(2.0f * g * h);  // SCALE = alpha/r = 2
}

// ---------------------------------------------------------------------------
// Kernel E: main GEMM, 128x256 tile, BK=64, 2 BLOCKS/CU — R13 body verbatim
// plus ONE change: a startup s_sleep(36) (~2300 cyc = half a tile-step) on
// one block of each co-resident pair to SEED anti-phase (block A drains LDS
// while block B runs MFMA). Key (b0&1)^((b0>>8)&1) differs under both
// co-residency hypotheses (consecutive b,b+1 or strided b,b+256). Sleep
// happens after prologue stage issue (loads in flight). Output bitwise-
// identical to R13 -> absmax must stay exactly 0.03125.
// ---------------------------------------------------------------------------
__global__ __launch_bounds__(256, 2) void k_main(
    const u16* __restrict__ xbf, const u16* __restrict__ wbf,
    const u16* __restrict__ G, const u16* __restrict__ BmT,
    const float* __restrict__ bias, float* __restrict__ out)
{
  __shared__ u16 lds[40960];  // A: [0,8192)  B0: [8192,24576)  B1: [24576,40960)
  const int tid = threadIdx.x;
  const int w = tid >> 6, lane = tid & 63;
  const int fr = lane & 15, fg = lane >> 4;
  const int wr = w >> 1, wc = w & 1;

  // XCD map (512 blocks): xcd = b0&7 gets m-groups [xcd*8..xcd*8+8) x all n,
  // n-minor within group (A-panel 512KB reused by 8 consecutive blocks, L2).
  const int b0 = blockIdx.x;
  const int xcd = b0 & 7, i = b0 >> 3;
  const int mBase = (xcd * 8 + (i >> 3)) * 128;   // 64 m-tiles
  const int nBase = (i & 7) * 256;                //  8 n-tiles

  // staging addressing (linear LDS dest; swizzled global source col)
  const int rl = lane >> 3;                 // 0..7
  const int ce = ((lane & 7) ^ rl) << 3;    // source col elems (XOR swizzle)
  // ds_read addressing (same XOR involution)
  const int swz = (fr & 7) << 3;
  const int colk0 = (fg * 8) ^ swz;
  const int colk1 = (32 + fg * 8) ^ swz;
  const int aOff = (wr * 64 + fr) * 64;
  const int bOff = (wc * 128 + fr) * 64;

  // running source pointers (+=64 per tile staged)
  const u16* pA = xbf + (mBase + w * 8 + rl) * 2048 + ce;
  const u16* pB = wbf + (nBase + w * 8 + rl) * 2048 + ce;

  f32x4 acc[4][8];
  const f32x4 zero = {0.f, 0.f, 0.f, 0.f};
#pragma unroll
  for (int mi = 0; mi < 4; ++mi)
#pragma unroll
    for (int nj = 0; nj < 8; ++nj) acc[mi][nj] = zero;

  short8 a[4][2];      // A(t) full per-wave tile in regs
  short8 U[2][2], V[2][2];  // B nj-pair ping-pong

#define LGKM(N) asm volatile("s_waitcnt lgkmcnt(" #N ")" ::: "memory")
#define VMC(N)  asm volatile("s_waitcnt vmcnt(" #N ")" ::: "memory")
#define BAR()   __builtin_amdgcn_s_barrier()

  // stage A(next): 4 GLL16 (rows i*32+w*8+rl), dst linear A-buf
#define SA() { GLL16(pA,          lds + w * 512);                             \
               GLL16(pA + 65536,  lds + 2048 + w * 512);                      \
               GLL16(pA + 131072, lds + 4096 + w * 512);                      \
               GLL16(pA + 196608, lds + 6144 + w * 512);                      \
               pA += 64; }
  // stage B(next) halves into Bnxt (BOFF = 8192 + ((t+1)&1)*16384)
#define SB_LO(BOFF) { GLL16(pB,          lds + (BOFF) + w * 512);             \
                      GLL16(pB + 65536,  lds + (BOFF) + 2048 + w * 512);      \
                      GLL16(pB + 131072, lds + (BOFF) + 4096 + w * 512);      \
                      GLL16(pB + 196608, lds + (BOFF) + 6144 + w * 512); }
#define SB_HI(BOFF) { GLL16(pB + 262144, lds + (BOFF) + 8192 + w * 512);      \
                      GLL16(pB + 327680, lds + (BOFF) + 10240 + w * 512);     \
                      GLL16(pB + 393216, lds + (BOFF) + 12288 + w * 512);     \
                      GLL16(pB + 458752, lds + (BOFF) + 14336 + w * 512);     \
                      pB += 64; }

#define RDA()                                                                 \
  _Pragma("unroll")                                                           \
  for (int mi = 0; mi < 4; ++mi) {                                            \
    a[mi][0] = *(const short8*)(lds + aOff + mi * 1024 + colk0);              \
    a[mi][1] = *(const short8*)(lds + aOff + mi * 1024 + colk1);              \
  }

#define RDB2(DST, BOFF, NJ0)                                                  \
  DST[0][0] = *(const short8*)(lds + (BOFF) + bOff + (NJ0) * 1024 + colk0);   \
  DST[0][1] = *(const short8*)(lds + (BOFF) + bOff + (NJ0) * 1024 + colk1);   \
  DST[1][0] = *(const short8*)(lds + (BOFF) + bOff + ((NJ0)+1) * 1024 + colk0);\
  DST[1][1] = *(const short8*)(lds + (BOFF) + bOff + ((NJ0)+1) * 1024 + colk1);

#define MFMAP(BV, NJ0)                                                        \
  __builtin_amdgcn_s_setprio(1);                                              \
  _Pragma("unroll")                                                           \
  for (int kk = 0; kk < 2; ++kk)                                              \
    _Pragma("unroll")                                                         \
    for (int mi = 0; mi < 4; ++mi)                                            \
      _Pragma("unroll")                                                       \
      for (int j = 0; j < 2; ++j)                                             \
        acc[mi][(NJ0) + j] = __builtin_amdgcn_mfma_f32_16x16x32_bf16(         \
            a[mi][kk], BV[j][kk], acc[mi][(NJ0) + j], 0, 0, 0);               \
  __builtin_amdgcn_s_setprio(0);

  // TILE: BCUR/BNXT = u16 offsets of current/next B buffer
#define TILE(BCUR, BNXT, SA_STMT, SBL_STMT, SBH_STMT)                         \
  {                                                                           \
    /* p0 */                                                                  \
    VMC(0);                                                                   \
    BAR();                                                                    \
    RDB2(U, BCUR, 0)                                                          \
    RDA()                                                                     \
    RDB2(V, BCUR, 2)                                                          \
    LGKM(4);                                                                  \
    MFMAP(U, 0)                                                               \
    BAR();                                                                    \
    /* p1 */                                                                  \
    SA_STMT                                                                   \
    RDB2(U, BCUR, 4)                                                          \
    LGKM(4);                                                                  \
    MFMAP(V, 2)                                                               \
    /* p2 */                                                                  \
    SBL_STMT                                                                  \
    RDB2(V, BCUR, 6)                                                          \
    LGKM(4);                                                                  \
    MFMAP(U, 4)                                                               \
    /* p3 */                                                                  \
    SBH_STMT                                                                  \
    LGKM(0);                                                                  \
    MFMAP(V, 6)                                                               \
  }

  // ---- prologue: stage A(0) + B(0) -> B0 (12 loads)
  SA()
  SB_LO(8192) SB_HI(8192)

  // ---- anti-phase seed: half-tile sleep for one of each co-resident pair
  if (((b0 & 1) ^ ((b0 >> 8) & 1)) != 0) {
    asm volatile("s_sleep 36");
  }

  // tiles 0..29 (pairs): Bcur parity t&1, stages regular
#pragma unroll 1
  for (int tt = 0; tt < 15; ++tt) {
    TILE(8192, 24576, SA(), SB_LO(24576), SB_HI(24576))     // t even
    TILE(24576, 8192, SA(), SB_LO(8192), SB_HI(8192))       // t odd
  }
  // ---- tile 30 (Bcur=B0): regular stages (A31, B31 -> B1)
  TILE(8192, 24576, SA(), SB_LO(24576), SB_HI(24576))
  // ---- tile 31 (Bcur=B1): stage A(32)<-G, B(32)<-BmT -> B0
  {
    const u16* pG = G + (mBase + w * 8 + rl) * 64 + ce;
    const u16* pT = BmT + (nBase + w * 8 + rl) * 64 + ce;
    TILE(24576, 8192,
         { GLL16(pG,        lds + w * 512);
           GLL16(pG + 2048, lds + 2048 + w * 512);
           GLL16(pG + 4096, lds + 4096 + w * 512);
           GLL16(pG + 6144, lds + 6144 + w * 512); },
         { GLL16(pT,        lds + 8192 + w * 512);
           GLL16(pT + 2048, lds + 8192 + 2048 + w * 512);
           GLL16(pT + 4096, lds + 8192 + 4096 + w * 512);
           GLL16(pT + 6144, lds + 8192 + 6144 + w * 512); },
         { GLL16(pT + 8192,  lds + 8192 + 8192 + w * 512);
           GLL16(pT + 10240, lds + 8192 + 10240 + w * 512);
           GLL16(pT + 12288, lds + 8192 + 12288 + w * 512);
           GLL16(pT + 14336, lds + 8192 + 14336 + w * 512); })
  }
  // ---- tile 32 (LoRA, Bcur=B0): no stages
  TILE(8192, 24576, {}, {}, {})

  // ---- epilogue: bias add + store
#pragma unroll
  for (int nj = 0; nj < 8; ++nj) {
    const int n = nBase + wc * 128 + nj * 16 + fr;
    const float bv = bias[n];
#pragma unroll
    for (int mi = 0; mi < 4; ++mi) {
      const int m = mBase + wr * 64 + mi * 16 + fg * 4;
#pragma unroll
      for (int r = 0; r < 4; ++r)
        out[(m + r) * 2048 + n] = acc[mi][nj][r] + bv;
    }
  }
#undef TILE
#undef MFMAP
#undef RDB2
#undef RDA
#undef SB_HI
#undef SB_LO
#undef SA
#undef BAR
#undef VMC
#undef LGKM
}

// ---------------------------------------------------------------------------
extern "C" void kernel_launch(void* const* d_in, const int* in_sizes, int n_in,
                              void* d_out, int out_size, void* d_ws, size_t ws_size,
                              hipStream_t stream) {
  const float* x  = (const float*)d_in[0];   // [4,2048,2048]
  const float* Wb = (const float*)d_in[1];   // [2048,2048]
  const float* bb = (const float*)d_in[2];   // [2048]
  const float* Wr = (const float*)d_in[3];   // [8,2048]
  const float* Aw = (const float*)d_in[4];   // [8,8,2048] == [64][2048]
  const float* Bw = (const float*)d_in[5];   // [8,2048,8]

  char* ws = (char*)d_ws;
  u16*   xbf  = (u16*)  (ws + 0);            // 33,554,432 B
  u16*   wbf  = (u16*)  (ws + 33554432);     //  8,388,608 B
  u16*   aabf = (u16*)  (ws + 41943040);     //    262,144 B
  u16*   bmt  = (u16*)  (ws + 42205184);     //    262,144 B
  float* lgt  = (float*)(ws + 42467328);     //    262,144 B
  u16*   G    = (u16*)  (ws + 42729472);     //  1,048,576 B
  // h-partials [8][8192][64] bf16 (8.4 MB) live in d_out; fully consumed by
  // k_topk before k_main overwrites all of d_out. Same-stream ordering.
  u16*   P   = (u16*)d_out;
  float* out = (float*)d_out;

  hipLaunchKernelGGL(k_pre,   dim3(512),   dim3(512), 0, stream,
                     x, Wr, Wb, Aw, Bw, xbf, lgt, wbf, aabf, bmt);
  hipLaunchKernelGGL(k_hgemm, dim3(32, 8), dim3(256), 0, stream, xbf, aabf, P);
  hipLaunchKernelGGL(k_topk,  dim3(2048),  dim3(256), 0, stream, lgt, P, G);
  hipLaunchKernelGGL(k_main,  dim3(512),   dim3(256), 0, stream,
                     xbf, wbf, G, bmt, bb, out);
}